// Round 7
// baseline (1811.359 us; speedup 1.0000x reference)
//
#include <hip/hip_runtime.h>

#define BATCH 256
#define TSTEPS 4096
#define HID 136
#define HPADH 144     // h buffer padded to 144 halves (288 B); halves 136..143 stay 0
#define NPAIR 68      // 136 rows = 68 h2-pairs
#define ODIM 68
#define THREADS 128   // 2 waves; wave0: pairs 0..63, wave1: pairs 64..67

typedef _Float16 h2 __attribute__((ext_vector_type(2)));

__device__ __forceinline__ float fast_tanh(float z) {
    float az = fabsf(z);
    float e = __expf(-2.0f * az);
    float r = (1.0f - e) * __builtin_amdgcn_rcpf(1.0f + e);
    return copysignf(r, z);
}

__device__ __forceinline__ h2 bc_h2(unsigned int u) {
    union { unsigned int u; h2 h; } c; c.u = u; return c.h;
}

// One step: read HR (broadcast chunks), 136 dot2 for this lane's two rows,
// tanh, one ds_write_b32 of the own h2 pair. One barrier.
#define RNN_STEP(HR, HW, T)                                                    \
    {                                                                          \
        float2 xv = *(const float2*)(xs + 2 * (T));                            \
        const uint4* hb = (const uint4*)(HR);                                  \
        float a0 = 0.f, a1 = 0.f;                                              \
        _Pragma("unroll")                                                      \
        for (int c = 0; c < 17; ++c) {                                         \
            uint4 q = hb[c];              /* uniform addr -> broadcast b128 */ \
            h2 e0 = bc_h2(q.x), e1 = bc_h2(q.y);                               \
            h2 e2 = bc_h2(q.z), e3 = bc_h2(q.w);                               \
            a0 = __builtin_amdgcn_fdot2(e0, w0[4 * c + 0], a0, false);         \
            a1 = __builtin_amdgcn_fdot2(e0, w1[4 * c + 0], a1, false);         \
            a0 = __builtin_amdgcn_fdot2(e1, w0[4 * c + 1], a0, false);         \
            a1 = __builtin_amdgcn_fdot2(e1, w1[4 * c + 1], a1, false);         \
            a0 = __builtin_amdgcn_fdot2(e2, w0[4 * c + 2], a0, false);         \
            a1 = __builtin_amdgcn_fdot2(e2, w1[4 * c + 2], a1, false);         \
            a0 = __builtin_amdgcn_fdot2(e3, w0[4 * c + 3], a0, false);         \
            a1 = __builtin_amdgcn_fdot2(e3, w1[4 * c + 3], a1, false);         \
        }                                                                      \
        float z0 = fmaf(xv.x, wx00, fmaf(xv.y, wx01, bias0)) + a0;             \
        float z1 = fmaf(xv.x, wx10, fmaf(xv.y, wx11, bias1)) + a1;             \
        h2 hw;                                                                 \
        hw.x = (_Float16)fast_tanh(z0);                                        \
        hw.y = (_Float16)fast_tanh(z1);                                        \
        if (valid) ((h2*)(HW))[p] = hw;    /* ds_write_b32 at byte 4p */       \
        __syncthreads();                                                       \
    }

__global__ __launch_bounds__(THREADS)
void rnn_fused_kernel(const float* __restrict__ x,
                      const float* __restrict__ W_ih,
                      const float* __restrict__ W_hh,
                      const float* __restrict__ b_ih,
                      const float* __restrict__ b_hh,
                      const float* __restrict__ W_fc,
                      const float* __restrict__ b_fc,
                      float* __restrict__ out)
{
    __shared__ __align__(16) float xs[TSTEPS * 2];      // 32 KB: x[b,:,:]
    __shared__ __align__(16) _Float16 hA[HPADH];
    __shared__ __align__(16) _Float16 hB[HPADH];

    const int b   = blockIdx.x;
    const int tid = threadIdx.x;
    const int p   = tid;                 // pair index 0..127 (valid < 68)
    const bool valid = (p < NPAIR);
    const int pp  = valid ? p : 0;       // clamped for weight loads
    const int r0  = 2 * pp;
    const int r1  = 2 * pp + 1;

    // ---- persistent W_hh rows r0, r1 as f16 pairs: 2 x 68 h2 = 136 VGPR ----
    h2 w0[NPAIR], w1[NPAIR];
#pragma unroll
    for (int k = 0; k < NPAIR; ++k) {
        w0[k] = h2{(_Float16)W_hh[r0 * HID + 2 * k],
                   (_Float16)W_hh[r0 * HID + 2 * k + 1]};
        w1[k] = h2{(_Float16)W_hh[r1 * HID + 2 * k],
                   (_Float16)W_hh[r1 * HID + 2 * k + 1]};
    }
    const float wx00 = W_ih[r0 * 2 + 0], wx01 = W_ih[r0 * 2 + 1];
    const float wx10 = W_ih[r1 * 2 + 0], wx11 = W_ih[r1 * 2 + 1];
    const float bias0 = b_ih[r0] + b_hh[r0];
    const float bias1 = b_ih[r1] + b_hh[r1];

    // ---- stage x[b] into LDS (coalesced float4); zero h buffers ----
    {
        const float4* xg = (const float4*)(x + (size_t)b * (TSTEPS * 2));
        float4* xl = (float4*)xs;
#pragma unroll
        for (int i = 0; i < TSTEPS * 2 / 4 / THREADS; ++i)
            xl[i * THREADS + tid] = xg[i * THREADS + tid];
    }
    if (tid < HPADH / 2) {              // 72 threads zero both buffers (h2)
        ((h2*)hA)[tid] = h2{(_Float16)0.f, (_Float16)0.f};
        ((h2*)hB)[tid] = h2{(_Float16)0.f, (_Float16)0.f};
    }
    __syncthreads();

    // ---- recurrence, unrolled x2 (fixed buffers), 1 barrier per step ----
    for (int t = 0; t < TSTEPS; t += 2) {
        RNN_STEP(hA, hB, t);
        RNN_STEP(hB, hA, t + 1);
    }
    // TSTEPS even -> final h in hA

    // ---- final head: out[b][o] = h . W_fc[o,:] + b_fc[o] ----
    if (tid < ODIM) {
        const int o = tid;
        float s = b_fc[o];
#pragma unroll 8
        for (int k = 0; k < HID; ++k)
            s = fmaf((float)hA[k], W_fc[o * HID + k], s);
        out[b * ODIM + o] = s;
    }
}

extern "C" void kernel_launch(void* const* d_in, const int* in_sizes, int n_in,
                              void* d_out, int out_size, void* d_ws, size_t ws_size,
                              hipStream_t stream) {
    const float* x    = (const float*)d_in[0];
    const float* W_ih = (const float*)d_in[1];
    const float* W_hh = (const float*)d_in[2];
    const float* b_ih = (const float*)d_in[3];
    const float* b_hh = (const float*)d_in[4];
    const float* W_fc = (const float*)d_in[5];
    const float* b_fc = (const float*)d_in[6];
    float* out = (float*)d_out;

    rnn_fused_kernel<<<BATCH, THREADS, 0, stream>>>(x, W_ih, W_hh, b_ih, b_hh,
                                                    W_fc, b_fc, out);
}